// Round 1
// baseline (4592.392 us; speedup 1.0000x reference)
//
#include <hip/hip_runtime.h>

// ---------------------------------------------------------------------------
// GNN scorer: 3x (edge message + scatter-add + node apply) -> node_sum
//             VM MLP folded to vm_sum via w2sum trick -> sigmoid scores
// fp32 baseline, correctness-first.
// ---------------------------------------------------------------------------

// ---- edge message: m = relu([h[src]; ef] @ Wm + bm); atomicAdd into neigh[dst]
template<int D, int DE, int OUT, int SH, int SN>
__global__ __launch_bounds__(256) void edge_msg(
    const float* __restrict__ h, const float* __restrict__ ef,
    const int* __restrict__ src, const int* __restrict__ dst,
    const float* __restrict__ Wm, const float* __restrict__ bm,
    float* __restrict__ neigh, int nE)
{
    constexpr int KW  = D + DE;
    constexpr int LPE = (OUT <= 32) ? 32 : 64;   // lanes per edge-group
    constexpr int GPB = 256 / LPE;               // groups per block
    constexpr int EPW = 4;                       // edges per group-iteration

    __shared__ float Wl[KW * OUT];
    __shared__ float bl[OUT];
    for (int i = threadIdx.x; i < KW * OUT; i += 256) Wl[i] = Wm[i];
    for (int i = threadIdx.x; i < OUT; i += 256) bl[i] = bm[i];
    __syncthreads();

    const int lane = threadIdx.x % LPE;
    const int grp  = threadIdx.x / LPE;
    const int o    = (lane < OUT) ? lane : 0;
    const float bias = bl[o];

    const long long step = (long long)gridDim.x * GPB * EPW;
    for (long long e0 = ((long long)blockIdx.x * GPB + grp) * EPW; e0 < nE; e0 += step) {
        const float* hr[EPW];
        const float* er[EPW];
        bool val[EPW];
        #pragma unroll
        for (int i = 0; i < EPW; i++) {
            long long e = e0 + i;
            val[i] = (e < nE);
            long long ec = val[i] ? e : (long long)(nE - 1);
            hr[i] = h + (long long)src[ec] * SH;
            er[i] = ef + ec * DE;
        }
        float acc[EPW];
        #pragma unroll
        for (int i = 0; i < EPW; i++) acc[i] = bias;

        constexpr int D4 = D & ~3;
        #pragma unroll 4
        for (int k = 0; k < D4; k += 4) {
            const float w0 = Wl[(k + 0) * OUT + o];
            const float w1 = Wl[(k + 1) * OUT + o];
            const float w2 = Wl[(k + 2) * OUT + o];
            const float w3 = Wl[(k + 3) * OUT + o];
            #pragma unroll
            for (int i = 0; i < EPW; i++) {
                float4 v = *reinterpret_cast<const float4*>(hr[i] + k);
                acc[i] = fmaf(v.x, w0, acc[i]);
                acc[i] = fmaf(v.y, w1, acc[i]);
                acc[i] = fmaf(v.z, w2, acc[i]);
                acc[i] = fmaf(v.w, w3, acc[i]);
            }
        }
        #pragma unroll
        for (int k = D4; k < D; k++) {
            const float w = Wl[k * OUT + o];
            #pragma unroll
            for (int i = 0; i < EPW; i++) acc[i] = fmaf(hr[i][k], w, acc[i]);
        }
        #pragma unroll 4
        for (int j = 0; j < DE; j += 4) {
            const float w0 = Wl[(D + j + 0) * OUT + o];
            const float w1 = Wl[(D + j + 1) * OUT + o];
            const float w2 = Wl[(D + j + 2) * OUT + o];
            const float w3 = Wl[(D + j + 3) * OUT + o];
            #pragma unroll
            for (int i = 0; i < EPW; i++) {
                float4 v = *reinterpret_cast<const float4*>(er[i] + j);
                acc[i] = fmaf(v.x, w0, acc[i]);
                acc[i] = fmaf(v.y, w1, acc[i]);
                acc[i] = fmaf(v.z, w2, acc[i]);
                acc[i] = fmaf(v.w, w3, acc[i]);
            }
        }
        if (lane < OUT) {
            #pragma unroll
            for (int i = 0; i < EPW; i++) {
                if (val[i]) {
                    int d2 = dst[e0 + i];
                    atomicAdd(&neigh[(long long)d2 * SN + lane], fmaxf(acc[i], 0.f));
                }
            }
        }
    }
}

// ---- node apply: out = relu([h; neigh] @ Wa + ba); optionally reduced to row-sum
template<int DH, int DN, int OUT, int SH, int SN, int SO, bool SUMOUT>
__global__ __launch_bounds__(256) void node_apply(
    const float* __restrict__ h, const float* __restrict__ neigh,
    const float* __restrict__ Wa, const float* __restrict__ ba,
    float* __restrict__ out, int nN)
{
    constexpr int KW  = DH + DN;
    constexpr int LPE = (OUT <= 32) ? 32 : 64;
    constexpr int GPB = 256 / LPE;

    __shared__ float Wl[KW * OUT];
    __shared__ float bl[OUT];
    for (int i = threadIdx.x; i < KW * OUT; i += 256) Wl[i] = Wa[i];
    for (int i = threadIdx.x; i < OUT; i += 256) bl[i] = ba[i];
    __syncthreads();

    const int lane = threadIdx.x % LPE;
    const int grp  = threadIdx.x / LPE;
    const int o    = (lane < OUT) ? lane : 0;

    for (int n = blockIdx.x * GPB + grp; n < nN; n += gridDim.x * GPB) {
        const float* hr = h + (long long)n * SH;
        const float* nr = neigh + (long long)n * SN;
        float acc = bl[o];

        constexpr int DH4 = DH & ~3;
        #pragma unroll 4
        for (int k = 0; k < DH4; k += 4) {
            float4 v = *reinterpret_cast<const float4*>(hr + k);
            acc = fmaf(v.x, Wl[(k + 0) * OUT + o], acc);
            acc = fmaf(v.y, Wl[(k + 1) * OUT + o], acc);
            acc = fmaf(v.z, Wl[(k + 2) * OUT + o], acc);
            acc = fmaf(v.w, Wl[(k + 3) * OUT + o], acc);
        }
        #pragma unroll
        for (int k = DH4; k < DH; k++) acc = fmaf(hr[k], Wl[k * OUT + o], acc);

        constexpr int DN4 = DN & ~3;
        #pragma unroll 4
        for (int j = 0; j < DN4; j += 4) {
            float4 v = *reinterpret_cast<const float4*>(nr + j);
            acc = fmaf(v.x, Wl[(DH + j + 0) * OUT + o], acc);
            acc = fmaf(v.y, Wl[(DH + j + 1) * OUT + o], acc);
            acc = fmaf(v.z, Wl[(DH + j + 2) * OUT + o], acc);
            acc = fmaf(v.w, Wl[(DH + j + 3) * OUT + o], acc);
        }
        #pragma unroll
        for (int j = DN4; j < DN; j++) acc = fmaf(nr[j], Wl[(DH + j) * OUT + o], acc);

        acc = fmaxf(acc, 0.f);
        if (SUMOUT) {
            float r = (lane < OUT) ? acc : 0.f;
            #pragma unroll
            for (int off = LPE / 2; off > 0; off >>= 1) r += __shfl_down(r, off);
            if (lane == 0) out[n] = r;
        } else {
            if (lane < OUT) out[(long long)n * SO + lane] = acc;
        }
    }
}

// ---- w2sum[j] = sum_o Wmlp2[j][o]; w2sum[128] = sum_o bmlp2[o]
__global__ void w2sum_kernel(const float* __restrict__ W2, const float* __restrict__ b2,
                             float* __restrict__ w2s)
{
    int j = threadIdx.x;  // 128 threads
    float s = 0.f;
    for (int o = 0; o < 64; o++) s += W2[j * 64 + o];
    w2s[j] = s;
    if (j == 0) {
        float bs = 0.f;
        for (int o = 0; o < 64; o++) bs += b2[o];
        w2s[128] = bs;
    }
}

// ---- vm_sum[v] = relu(vm[v] @ W1 + b1) . w2sum + b2sum
__global__ __launch_bounds__(256) void vm_kernel(
    const float* __restrict__ vmf, const float* __restrict__ W1,
    const float* __restrict__ b1, const float* __restrict__ w2s,
    float* __restrict__ vm_sum, int nV)
{
    const int lane = threadIdx.x & 63;
    const int grp  = threadIdx.x >> 6;
    for (int v = blockIdx.x * 4 + grp; v < nV; v += gridDim.x * 4) {
        const float* vr = vmf + (long long)v * 64;
        float a0 = b1[lane], a1 = b1[lane + 64];
        #pragma unroll 4
        for (int k = 0; k < 64; k += 4) {
            float4 x = *reinterpret_cast<const float4*>(vr + k);
            a0 = fmaf(x.x, W1[(k + 0) * 128 + lane], a0);
            a0 = fmaf(x.y, W1[(k + 1) * 128 + lane], a0);
            a0 = fmaf(x.z, W1[(k + 2) * 128 + lane], a0);
            a0 = fmaf(x.w, W1[(k + 3) * 128 + lane], a0);
            a1 = fmaf(x.x, W1[(k + 0) * 128 + lane + 64], a1);
            a1 = fmaf(x.y, W1[(k + 1) * 128 + lane + 64], a1);
            a1 = fmaf(x.z, W1[(k + 2) * 128 + lane + 64], a1);
            a1 = fmaf(x.w, W1[(k + 3) * 128 + lane + 64], a1);
        }
        float part = fmaxf(a0, 0.f) * w2s[lane] + fmaxf(a1, 0.f) * w2s[lane + 64];
        #pragma unroll
        for (int off = 32; off > 0; off >>= 1) part += __shfl_down(part, off);
        if (lane == 0) vm_sum[v] = part + w2s[128];
    }
}

// ---- scores
__global__ __launch_bounds__(256) void score_kernel(
    const int* __restrict__ ec, const int* __restrict__ ev,
    const float* __restrict__ ns, const float* __restrict__ vs,
    float* __restrict__ out, int n)
{
    int i = blockIdx.x * blockDim.x + threadIdx.x;
    if (i < n) {
        float x = ns[ec[i]] + vs[ev[i]];
        out[i] = 1.f / (1.f + expf(-x));
    }
}

extern "C" void kernel_launch(void* const* d_in, const int* in_sizes, int n_in,
                              void* d_out, int out_size, void* d_ws, size_t ws_size,
                              hipStream_t stream)
{
    const float* comp = (const float*)d_in[0];
    const float* ef   = (const float*)d_in[1];
    const float* vmf  = (const float*)d_in[2];
    const int*   src  = (const int*)d_in[3];
    const int*   dst  = (const int*)d_in[4];
    const int*   ecmp = (const int*)d_in[5];
    const int*   evm  = (const int*)d_in[6];
    const float* Wm1 = (const float*)d_in[7];  const float* bm1 = (const float*)d_in[8];
    const float* Wa1 = (const float*)d_in[9];  const float* ba1 = (const float*)d_in[10];
    const float* Wm2 = (const float*)d_in[11]; const float* bm2 = (const float*)d_in[12];
    const float* Wa2 = (const float*)d_in[13]; const float* ba2 = (const float*)d_in[14];
    const float* Wm3 = (const float*)d_in[15]; const float* bm3 = (const float*)d_in[16];
    const float* Wa3 = (const float*)d_in[17]; const float* ba3 = (const float*)d_in[18];
    const float* W1  = (const float*)d_in[19]; const float* b1  = (const float*)d_in[20];
    const float* W2  = (const float*)d_in[21]; const float* b2  = (const float*)d_in[22];

    const int nN = in_sizes[0] / 128;
    const int nE = in_sizes[3];
    const int nV = in_sizes[2] / 64;
    const int nS = in_sizes[5];

    // workspace layout (floats); strides padded to multiples of 4 for 16B-aligned rows
    float* ws = (float*)d_ws;
    float* h1       = ws;                        // nN * 52  (50 used)
    float* h2       = h1 + (size_t)nN * 52;      // nN * 28  (25 used)
    float* ng       = h2 + (size_t)nN * 28;      // nN * 64  (reused per layer)
    float* node_sum = ng + (size_t)nN * 64;      // nN
    float* vm_sum   = node_sum + nN;             // nV
    float* w2s      = vm_sum + nV;               // 129

    auto egrid = [&](int per_block) {
        long long b = ((long long)nE + per_block - 1) / per_block;
        return (int)(b < 4096 ? b : 4096);
    };
    const int agrid = 2048;

    // ---- Layer 1: D=128, OUT=50 (strides: h=128, neigh/h1=52)
    hipMemsetAsync(ng, 0, (size_t)nN * 52 * sizeof(float), stream);
    edge_msg<128, 64, 50, 128, 52><<<egrid(16), 256, 0, stream>>>(comp, ef, src, dst, Wm1, bm1, ng, nE);
    node_apply<128, 50, 50, 128, 52, 52, false><<<agrid, 256, 0, stream>>>(comp, ng, Wa1, ba1, h1, nN);

    // ---- Layer 2: D=50, OUT=25 (strides: h1=52, neigh/h2=28)
    hipMemsetAsync(ng, 0, (size_t)nN * 28 * sizeof(float), stream);
    edge_msg<50, 64, 25, 52, 28><<<egrid(32), 256, 0, stream>>>(h1, ef, src, dst, Wm2, bm2, ng, nE);
    node_apply<50, 25, 25, 52, 28, 28, false><<<agrid, 256, 0, stream>>>(h1, ng, Wa2, ba2, h2, nN);

    // ---- Layer 3: D=25, OUT=64 (strides: h2=28, neigh=64); apply fused to row-sum
    hipMemsetAsync(ng, 0, (size_t)nN * 64 * sizeof(float), stream);
    edge_msg<25, 64, 64, 28, 64><<<egrid(16), 256, 0, stream>>>(h2, ef, src, dst, Wm3, bm3, ng, nE);
    node_apply<25, 64, 64, 28, 64, 1, true><<<agrid, 256, 0, stream>>>(h2, ng, Wa3, ba3, node_sum, nN);

    // ---- VM tower (folded) + scores
    w2sum_kernel<<<1, 128, 0, stream>>>(W2, b2, w2s);
    vm_kernel<<<(nV + 3) / 4, 256, 0, stream>>>(vmf, W1, b1, w2s, vm_sum, nV);
    score_kernel<<<(nS + 255) / 256, 256, 0, stream>>>(ecmp, evm, node_sum, vm_sum, (float*)d_out, nS);
}

// Round 2
// 3144.889 us; speedup vs baseline: 1.4603x; 1.4603x over previous
//
#include <hip/hip_runtime.h>

// ---------------------------------------------------------------------------
// GNN scorer, restructured:
//   per layer: P = h @ Wm[:d] + bm          (node pre-GEMM, dense)
//              m = relu(P[src] + ef @ We)    (dense edge GEMM + gather)
//              ng[dst] += m                  (atomic scatter, skip zeros)
//              h' = relu([h ; ng] @ Wa + ba) (node apply; L3 fused to rowsum)
//   VM tower folded via w2sum trick; sigmoid scoring.
// All fp32. Unified LDS-tiled GEMM template, 128-row tiles, 256 threads.
// ---------------------------------------------------------------------------

// MODE: 0 = store linear (node_pre: P)            Y[r][o] = acc + b
//       1 = relu + store (node apply L1/L2)       Y[r][o] = relu(acc + b)
//       2 = relu + row-sum (node apply L3)        Y[r]    = sum_o relu(acc + b)
//       3 = edge: relu(acc + P[src]) -> atomicAdd into Y[dst] (skip zeros/pad)
template<int K0, int KP0, int K1, int KP1, int KC, int OUT, int NTC, int RPT, int MODE>
__global__ __launch_bounds__(256) void tile_gemm(
    const float* __restrict__ X0, int sx0,
    const float* __restrict__ X1, int sx1,
    const float* __restrict__ Wg, const float* __restrict__ Bg,
    const int* __restrict__ gsrc, const int* __restrict__ gdst,
    const float* __restrict__ P, int sp,
    float* __restrict__ Y, int sy, int nR)
{
    constexpr int KPT  = KP0 + KP1;       // padded total K
    constexpr int C4   = KC / 4;          // float4 cols per X chunk
    constexpr int OUTP = 4 * NTC;         // padded out width
    constexpr int NTR  = 256 / NTC;
    constexpr int TR   = NTR * RPT;       // tile rows
    static_assert(TR == 128, "tile must be 128 rows");
    static_assert(KPT % KC == 0, "KC must divide KPT");
    static_assert((KC & 3) == 0 && (KP0 & 3) == 0, "f4 alignment");

    __shared__ float4 Xl[TR * C4];
    __shared__ float4 Wl[KC * NTC];
    __shared__ float  __align__(16) bl[OUTP];
    __shared__ int    sl_src[128], sl_dst[128];

    const int tid = threadIdx.x;
    const int r0  = blockIdx.x * TR;

    for (int idx = tid; idx < OUTP; idx += 256)
        bl[idx] = (Bg != nullptr && idx < OUT) ? Bg[idx] : 0.f;
    if (MODE == 3 && tid < TR) {
        int gr = r0 + tid;
        sl_src[tid] = (gr < nR) ? gsrc[gr] : 0;
        sl_dst[tid] = (gr < nR) ? gdst[gr] : 0;
    }

    const int tc  = tid & (NTC - 1);
    const int tr  = tid / NTC;
    const int key = (RPT * tr) >> 3;   // swizzle key (constant across this thread's rows)

    float4 acc[RPT];
    #pragma unroll
    for (int i = 0; i < RPT; i++) acc[i] = make_float4(0.f, 0.f, 0.f, 0.f);

    for (int kc0 = 0; kc0 < KPT; kc0 += KC) {
        if (kc0 != 0) __syncthreads();
        // ---- stage X chunk (swizzled float4 layout: Xl[r][ (c + (r>>3)) % C4 ])
        for (int idx = tid; idx < TR * C4; idx += 256) {
            int r = idx / C4, c = idx - r * C4;
            int col = kc0 + 4 * c;
            int gr = r0 + r;
            float4 v = make_float4(0.f, 0.f, 0.f, 0.f);
            if (gr < nR) {
                if (KP1 == 0 || col < KP0)
                    v = *reinterpret_cast<const float4*>(X0 + (long long)gr * sx0 + col);
                else
                    v = *reinterpret_cast<const float4*>(X1 + (long long)gr * sx1 + (col - KP0));
            }
            int cs = c + ((r >> 3) % C4); if (cs >= C4) cs -= C4;
            Xl[r * C4 + cs] = v;
        }
        // ---- stage W chunk (rows kc0..kc0+KC-1, zero-pad K gaps and out cols)
        for (int idx = tid; idx < KC * OUTP; idx += 256) {
            int kl = idx / OUTP, o = idx - kl * OUTP;
            int k = kc0 + kl;
            float v = 0.f;
            if (o < OUT) {
                if (k < KP0) { if (k < K0) v = Wg[k * OUT + o]; }
                else { int kk = k - KP0; if (kk < K1) v = Wg[(K0 + kk) * OUT + o]; }
            }
            ((float*)Wl)[kl * OUTP + o] = v;
        }
        __syncthreads();

        const int km = key % C4;
        #pragma unroll 4
        for (int k4 = 0; k4 < C4; k4++) {
            int cs = k4 + km; if (cs >= C4) cs -= C4;
            float4 x[RPT];
            #pragma unroll
            for (int i = 0; i < RPT; i++)
                x[i] = Xl[(RPT * tr + i) * C4 + cs];
            #pragma unroll
            for (int kk = 0; kk < 4; kk++) {
                float4 w = Wl[(4 * k4 + kk) * NTC + tc];
                #pragma unroll
                for (int i = 0; i < RPT; i++) {
                    float xs = (kk == 0) ? x[i].x : (kk == 1) ? x[i].y
                             : (kk == 2) ? x[i].z : x[i].w;
                    acc[i].x = fmaf(xs, w.x, acc[i].x);
                    acc[i].y = fmaf(xs, w.y, acc[i].y);
                    acc[i].z = fmaf(xs, w.z, acc[i].z);
                    acc[i].w = fmaf(xs, w.w, acc[i].w);
                }
            }
        }
    }

    const float4 b4 = reinterpret_cast<float4*>(bl)[tc];

    if (MODE == 0 || MODE == 1) {
        if (4 * tc < OUT) {
            #pragma unroll
            for (int i = 0; i < RPT; i++) {
                int gr = r0 + RPT * tr + i;
                if (gr < nR) {
                    float4 v;
                    v.x = acc[i].x + b4.x; v.y = acc[i].y + b4.y;
                    v.z = acc[i].z + b4.z; v.w = acc[i].w + b4.w;
                    if (MODE == 1) {
                        v.x = fmaxf(v.x, 0.f); v.y = fmaxf(v.y, 0.f);
                        v.z = fmaxf(v.z, 0.f); v.w = fmaxf(v.w, 0.f);
                    }
                    *reinterpret_cast<float4*>(Y + (long long)gr * sy + 4 * tc) = v;
                }
            }
        }
    } else if (MODE == 2) {
        #pragma unroll
        for (int i = 0; i < RPT; i++) {
            int gr = r0 + RPT * tr + i;
            float s = fmaxf(acc[i].x + b4.x, 0.f) + fmaxf(acc[i].y + b4.y, 0.f)
                    + fmaxf(acc[i].z + b4.z, 0.f) + fmaxf(acc[i].w + b4.w, 0.f);
            #pragma unroll
            for (int off = 1; off < NTC; off <<= 1) s += __shfl_xor(s, off);
            if (tc == 0 && gr < nR) Y[gr] = s;
        }
    } else {  // MODE 3: edge epilogue
        #pragma unroll
        for (int i = 0; i < RPT; i++) {
            int r = RPT * tr + i;
            int gr = r0 + r;
            if (gr < nR) {
                int s = sl_src[r];
                float4 p = *reinterpret_cast<const float4*>(P + (long long)s * sp + 4 * tc);
                float vx = fmaxf(acc[i].x + p.x, 0.f);
                float vy = fmaxf(acc[i].y + p.y, 0.f);
                float vz = fmaxf(acc[i].z + p.z, 0.f);
                float vw = fmaxf(acc[i].w + p.w, 0.f);
                int d2 = sl_dst[r];
                float* nb = Y + (long long)d2 * sy + 4 * tc;
                int o = 4 * tc;
                if (o + 0 < OUT && vx > 0.f) atomicAdd(nb + 0, vx);
                if (o + 1 < OUT && vy > 0.f) atomicAdd(nb + 1, vy);
                if (o + 2 < OUT && vz > 0.f) atomicAdd(nb + 2, vz);
                if (o + 3 < OUT && vw > 0.f) atomicAdd(nb + 3, vw);
            }
        }
    }
}

// ---- w2sum[j] = sum_o Wmlp2[j][o]; w2sum[128] = sum_o bmlp2[o]
__global__ void w2sum_kernel(const float* __restrict__ W2, const float* __restrict__ b2,
                             float* __restrict__ w2s)
{
    int j = threadIdx.x;  // 128 threads
    float s = 0.f;
    for (int o = 0; o < 64; o++) s += W2[j * 64 + o];
    w2s[j] = s;
    if (j == 0) {
        float bs = 0.f;
        for (int o = 0; o < 64; o++) bs += b2[o];
        w2s[128] = bs;
    }
}

// ---- vm_sum[v] = relu(vm[v] @ W1 + b1) . w2sum + b2sum
__global__ __launch_bounds__(256) void vm_kernel(
    const float* __restrict__ vmf, const float* __restrict__ W1,
    const float* __restrict__ b1, const float* __restrict__ w2s,
    float* __restrict__ vm_sum, int nV)
{
    const int lane = threadIdx.x & 63;
    const int grp  = threadIdx.x >> 6;
    for (int v = blockIdx.x * 4 + grp; v < nV; v += gridDim.x * 4) {
        const float* vr = vmf + (long long)v * 64;
        float a0 = b1[lane], a1 = b1[lane + 64];
        #pragma unroll 4
        for (int k = 0; k < 64; k += 4) {
            float4 x = *reinterpret_cast<const float4*>(vr + k);
            a0 = fmaf(x.x, W1[(k + 0) * 128 + lane], a0);
            a0 = fmaf(x.y, W1[(k + 1) * 128 + lane], a0);
            a0 = fmaf(x.z, W1[(k + 2) * 128 + lane], a0);
            a0 = fmaf(x.w, W1[(k + 3) * 128 + lane], a0);
            a1 = fmaf(x.x, W1[(k + 0) * 128 + lane + 64], a1);
            a1 = fmaf(x.y, W1[(k + 1) * 128 + lane + 64], a1);
            a1 = fmaf(x.z, W1[(k + 2) * 128 + lane + 64], a1);
            a1 = fmaf(x.w, W1[(k + 3) * 128 + lane + 64], a1);
        }
        float part = fmaxf(a0, 0.f) * w2s[lane] + fmaxf(a1, 0.f) * w2s[lane + 64];
        #pragma unroll
        for (int off = 32; off > 0; off >>= 1) part += __shfl_down(part, off);
        if (lane == 0) vm_sum[v] = part + w2s[128];
    }
}

// ---- scores
__global__ __launch_bounds__(256) void score_kernel(
    const int* __restrict__ ec, const int* __restrict__ ev,
    const float* __restrict__ ns, const float* __restrict__ vs,
    float* __restrict__ out, int n)
{
    int i = blockIdx.x * blockDim.x + threadIdx.x;
    if (i < n) {
        float x = ns[ec[i]] + vs[ev[i]];
        out[i] = 1.f / (1.f + expf(-x));
    }
}

extern "C" void kernel_launch(void* const* d_in, const int* in_sizes, int n_in,
                              void* d_out, int out_size, void* d_ws, size_t ws_size,
                              hipStream_t stream)
{
    const float* comp = (const float*)d_in[0];
    const float* ef   = (const float*)d_in[1];
    const float* vmf  = (const float*)d_in[2];
    const int*   src  = (const int*)d_in[3];
    const int*   dst  = (const int*)d_in[4];
    const int*   ecmp = (const int*)d_in[5];
    const int*   evm  = (const int*)d_in[6];
    const float* Wm1 = (const float*)d_in[7];  const float* bm1 = (const float*)d_in[8];
    const float* Wa1 = (const float*)d_in[9];  const float* ba1 = (const float*)d_in[10];
    const float* Wm2 = (const float*)d_in[11]; const float* bm2 = (const float*)d_in[12];
    const float* Wa2 = (const float*)d_in[13]; const float* ba2 = (const float*)d_in[14];
    const float* Wm3 = (const float*)d_in[15]; const float* bm3 = (const float*)d_in[16];
    const float* Wa3 = (const float*)d_in[17]; const float* ba3 = (const float*)d_in[18];
    const float* W1  = (const float*)d_in[19]; const float* b1  = (const float*)d_in[20];
    const float* W2  = (const float*)d_in[21]; const float* b2  = (const float*)d_in[22];

    const int nN = in_sizes[0] / 128;
    const int nE = in_sizes[3];
    const int nV = in_sizes[2] / 64;
    const int nS = in_sizes[5];

    // workspace: bufA(64w): h1(stride 52) then P3(64); bufB(64w): P1(64), P2(32), h2(28)
    float* ws = (float*)d_ws;
    float* bufA     = ws;
    float* bufB     = bufA + (size_t)nN * 64;
    float* ng       = bufB + (size_t)nN * 64;    // neigh accumulator, stride 64, reused
    float* node_sum = ng + (size_t)nN * 64;      // nN
    float* vm_sum   = node_sum + nN;             // nV
    float* w2s      = vm_sum + nV;               // 129

    float* h1 = bufA;   // stride 52
    float* h2 = bufB;   // stride 28
    float* P1 = bufB;   // stride 64
    float* P2 = bufB;   // stride 32
    float* P3 = bufA;   // stride 64

    const int ngrid = (nN + 127) / 128;
    const int egrid = (nE + 127) / 128;
    const size_t ngbytes = (size_t)nN * 64 * sizeof(float);

    // ================= Layer 1 (D=128 -> 50) =================
    hipMemsetAsync(ng, 0, ngbytes, stream);
    // P1 = comp @ Wm1[:128] + bm1
    tile_gemm<128,128, 0,0, 64, 50, 16, 8, 0><<<ngrid, 256, 0, stream>>>(
        comp, 128, nullptr, 0, Wm1, bm1, nullptr, nullptr, nullptr, 0, P1, 64, nN);
    // ng[dst] += relu(P1[src] + ef @ Wm1[128:])
    tile_gemm<64,64, 0,0, 64, 50, 16, 8, 3><<<egrid, 256, 0, stream>>>(
        ef, 64, nullptr, 0, Wm1 + 128 * 50, nullptr, src, dst, P1, 64, ng, 64, nE);
    // h1 = relu([comp ; ng] @ Wa1 + ba1)
    tile_gemm<128,128, 50,52, 60, 50, 16, 8, 1><<<ngrid, 256, 0, stream>>>(
        comp, 128, ng, 64, Wa1, ba1, nullptr, nullptr, nullptr, 0, h1, 52, nN);

    // ================= Layer 2 (50 -> 25) =================
    hipMemsetAsync(ng, 0, ngbytes, stream);
    tile_gemm<50,52, 0,0, 52, 25, 8, 4, 0><<<ngrid, 256, 0, stream>>>(
        h1, 52, nullptr, 0, Wm2, bm2, nullptr, nullptr, nullptr, 0, P2, 32, nN);
    tile_gemm<64,64, 0,0, 64, 25, 8, 4, 3><<<egrid, 256, 0, stream>>>(
        ef, 64, nullptr, 0, Wm2 + 50 * 25, nullptr, src, dst, P2, 32, ng, 64, nE);
    tile_gemm<50,52, 25,28, 80, 25, 8, 4, 1><<<ngrid, 256, 0, stream>>>(
        h1, 52, ng, 64, Wa2, ba2, nullptr, nullptr, nullptr, 0, h2, 28, nN);

    // ================= Layer 3 (25 -> 64, fused rowsum) =================
    hipMemsetAsync(ng, 0, ngbytes, stream);
    tile_gemm<25,28, 0,0, 28, 64, 16, 8, 0><<<ngrid, 256, 0, stream>>>(
        h2, 28, nullptr, 0, Wm3, bm3, nullptr, nullptr, nullptr, 0, P3, 64, nN);
    tile_gemm<64,64, 0,0, 64, 64, 16, 8, 3><<<egrid, 256, 0, stream>>>(
        ef, 64, nullptr, 0, Wm3 + 25 * 64, nullptr, src, dst, P3, 64, ng, 64, nE);
    tile_gemm<25,28, 64,68, 48, 64, 16, 8, 2><<<ngrid, 256, 0, stream>>>(
        h2, 28, ng, 64, Wa3, ba3, nullptr, nullptr, nullptr, 0, node_sum, 1, nN);

    // ================= VM tower (folded) + scores =================
    w2sum_kernel<<<1, 128, 0, stream>>>(W2, b2, w2s);
    vm_kernel<<<(nV + 3) / 4, 256, 0, stream>>>(vmf, W1, b1, w2s, vm_sum, nV);
    score_kernel<<<(nS + 255) / 256, 256, 0, stream>>>(ecmp, evm, node_sum, vm_sum, (float*)d_out, nS);
}

// Round 3
// 1717.059 us; speedup vs baseline: 2.6746x; 1.8316x over previous
//
#include <hip/hip_runtime.h>

// ---------------------------------------------------------------------------
// GNN scorer, round 3:
//   One-time per launch: counting-sort edges by dst (hist/scan/scatter) ->
//   perm, srcp, dstp. Per layer:
//     P = h @ Wm[:d] + bm                       (node pre-GEMM)
//     ng[dst] += relu(P[srcp] + ef[perm] @ We)  (edge GEMM, sorted rows,
//                                                run-length-reduced atomics)
//     h' = relu([h ; ng] @ Wa + ba)             (apply; L3 fused to rowsum)
//   VM tower folded via w2sum; sigmoid scoring. All fp32.
// ---------------------------------------------------------------------------

// MODE: 0 = store linear (P)     1 = relu+store    2 = relu+rowsum
//       3 = edge: relu(acc + P[srcp]) run-reduced atomicAdd into Y[dstp]
// GX: gather X0 rows through gperm (edge kernels)
template<int K0, int KP0, int K1, int KP1, int KC, int OUT, int NTC, int RPT,
         int MODE, bool GX>
__global__ __launch_bounds__(256) void tile_gemm(
    const float* __restrict__ X0, int sx0,
    const float* __restrict__ X1, int sx1,
    const float* __restrict__ Wg, const float* __restrict__ Bg,
    const int* __restrict__ gperm,
    const int* __restrict__ gsrc, const int* __restrict__ gdst,
    const float* __restrict__ P, int sp,
    float* __restrict__ Y, int sy, int nR)
{
    constexpr int KPT  = KP0 + KP1;
    constexpr int C4   = KC / 4;
    constexpr int OUTP = 4 * NTC;
    constexpr int NTR  = 256 / NTC;
    constexpr int TR   = NTR * RPT;
    static_assert(TR == 128, "tile must be 128 rows");
    static_assert(KPT % KC == 0, "KC must divide KPT");
    static_assert((KC & 3) == 0 && (KP0 & 3) == 0, "f4 alignment");

    __shared__ float4 Xl[TR * C4];
    __shared__ float4 Wl[KC * NTC];
    __shared__ float  __align__(16) bl[OUTP];
    __shared__ int    sl_src[128], sl_dst[128];

    const int tid = threadIdx.x;
    const int r0  = blockIdx.x * TR;

    for (int idx = tid; idx < OUTP; idx += 256)
        bl[idx] = (Bg != nullptr && idx < OUT) ? Bg[idx] : 0.f;
    if (MODE == 3 && tid < TR) {
        int gr = r0 + tid;
        sl_src[tid] = (gr < nR) ? gsrc[gr] : 0;
        sl_dst[tid] = (gr < nR) ? gdst[gr] : -1;
    }

    const int tc  = tid & (NTC - 1);
    const int tr  = tid / NTC;
    const int key = (RPT * tr) >> 3;

    float4 acc[RPT];
    #pragma unroll
    for (int i = 0; i < RPT; i++) acc[i] = make_float4(0.f, 0.f, 0.f, 0.f);

    for (int kc0 = 0; kc0 < KPT; kc0 += KC) {
        if (kc0 != 0) __syncthreads();
        // ---- stage X chunk (swizzled: Xl[r][(c + (r>>3)) % C4])
        for (int idx = tid; idx < TR * C4; idx += 256) {
            int r = idx / C4, c = idx - r * C4;
            int col = kc0 + 4 * c;
            int gr = r0 + r;
            float4 v = make_float4(0.f, 0.f, 0.f, 0.f);
            if (gr < nR) {
                long long xr = GX ? (long long)gperm[gr] : (long long)gr;
                if (KP1 == 0 || col < KP0)
                    v = *reinterpret_cast<const float4*>(X0 + xr * sx0 + col);
                else
                    v = *reinterpret_cast<const float4*>(X1 + xr * sx1 + (col - KP0));
            }
            int cs = c + ((r >> 3) % C4); if (cs >= C4) cs -= C4;
            Xl[r * C4 + cs] = v;
        }
        // ---- stage W chunk (zero-pad K gaps and out cols)
        for (int idx = tid; idx < KC * OUTP; idx += 256) {
            int kl = idx / OUTP, o = idx - kl * OUTP;
            int k = kc0 + kl;
            float v = 0.f;
            if (o < OUT) {
                if (k < KP0) { if (k < K0) v = Wg[k * OUT + o]; }
                else { int kk = k - KP0; if (kk < K1) v = Wg[(K0 + kk) * OUT + o]; }
            }
            ((float*)Wl)[kl * OUTP + o] = v;
        }
        __syncthreads();

        const int km = key % C4;
        #pragma unroll 4
        for (int k4 = 0; k4 < C4; k4++) {
            int cs = k4 + km; if (cs >= C4) cs -= C4;
            float4 x[RPT];
            #pragma unroll
            for (int i = 0; i < RPT; i++)
                x[i] = Xl[(RPT * tr + i) * C4 + cs];
            #pragma unroll
            for (int kk = 0; kk < 4; kk++) {
                float4 w = Wl[(4 * k4 + kk) * NTC + tc];
                #pragma unroll
                for (int i = 0; i < RPT; i++) {
                    float xs = (kk == 0) ? x[i].x : (kk == 1) ? x[i].y
                             : (kk == 2) ? x[i].z : x[i].w;
                    acc[i].x = fmaf(xs, w.x, acc[i].x);
                    acc[i].y = fmaf(xs, w.y, acc[i].y);
                    acc[i].z = fmaf(xs, w.z, acc[i].z);
                    acc[i].w = fmaf(xs, w.w, acc[i].w);
                }
            }
        }
    }

    const float4 b4 = reinterpret_cast<float4*>(bl)[tc];
    const int o = 4 * tc;

    if (MODE == 0 || MODE == 1) {
        if (o < OUT) {
            #pragma unroll
            for (int i = 0; i < RPT; i++) {
                int gr = r0 + RPT * tr + i;
                if (gr < nR) {
                    float4 v;
                    v.x = acc[i].x + b4.x; v.y = acc[i].y + b4.y;
                    v.z = acc[i].z + b4.z; v.w = acc[i].w + b4.w;
                    if (MODE == 1) {
                        v.x = fmaxf(v.x, 0.f); v.y = fmaxf(v.y, 0.f);
                        v.z = fmaxf(v.z, 0.f); v.w = fmaxf(v.w, 0.f);
                    }
                    *reinterpret_cast<float4*>(Y + (long long)gr * sy + o) = v;
                }
            }
        }
    } else if (MODE == 2) {
        #pragma unroll
        for (int i = 0; i < RPT; i++) {
            int gr = r0 + RPT * tr + i;
            float s = fmaxf(acc[i].x + b4.x, 0.f) + fmaxf(acc[i].y + b4.y, 0.f)
                    + fmaxf(acc[i].z + b4.z, 0.f) + fmaxf(acc[i].w + b4.w, 0.f);
            #pragma unroll
            for (int off = 1; off < NTC; off <<= 1) s += __shfl_xor(s, off);
            if (tc == 0 && gr < nR) Y[gr] = s;
        }
    } else {  // MODE 3: edge epilogue with run-length-reduced atomics
        float4 run = make_float4(0.f, 0.f, 0.f, 0.f);
        int rund = -1;
        #pragma unroll
        for (int i = 0; i < RPT; i++) {
            int r = RPT * tr + i;
            int d = sl_dst[r];
            if (d >= 0) {
                int s = sl_src[r];
                float4 p = *reinterpret_cast<const float4*>(P + (long long)s * sp + o);
                float4 v;
                v.x = fmaxf(acc[i].x + p.x, 0.f);
                v.y = fmaxf(acc[i].y + p.y, 0.f);
                v.z = fmaxf(acc[i].z + p.z, 0.f);
                v.w = fmaxf(acc[i].w + p.w, 0.f);
                if (d != rund) {
                    if (rund >= 0) {
                        float* nb = Y + (long long)rund * sy + o;
                        if (o + 0 < OUT && run.x > 0.f) atomicAdd(nb + 0, run.x);
                        if (o + 1 < OUT && run.y > 0.f) atomicAdd(nb + 1, run.y);
                        if (o + 2 < OUT && run.z > 0.f) atomicAdd(nb + 2, run.z);
                        if (o + 3 < OUT && run.w > 0.f) atomicAdd(nb + 3, run.w);
                    }
                    run = v; rund = d;
                } else {
                    run.x += v.x; run.y += v.y; run.z += v.z; run.w += v.w;
                }
            }
        }
        if (rund >= 0) {
            float* nb = Y + (long long)rund * sy + o;
            if (o + 0 < OUT && run.x > 0.f) atomicAdd(nb + 0, run.x);
            if (o + 1 < OUT && run.y > 0.f) atomicAdd(nb + 1, run.y);
            if (o + 2 < OUT && run.z > 0.f) atomicAdd(nb + 2, run.z);
            if (o + 3 < OUT && run.w > 0.f) atomicAdd(nb + 3, run.w);
        }
    }
}

// ---------------- sort-by-dst (counting sort) ----------------
__global__ __launch_bounds__(256) void hist_kernel(
    const int* __restrict__ dst, int* __restrict__ deg, int nE)
{
    for (int e = blockIdx.x * 256 + threadIdx.x; e < nE; e += gridDim.x * 256)
        atomicAdd(&deg[dst[e]], 1);
}

__global__ __launch_bounds__(1024) void scan_kernel(
    const int* __restrict__ deg, int* __restrict__ rowp, int nN)
{
    __shared__ int wsum[16];
    __shared__ int carry;
    const int tid = threadIdx.x;
    if (tid == 0) carry = 0;
    __syncthreads();
    for (int base = 0; base < nN; base += 1024) {
        int x = (base + tid < nN) ? deg[base + tid] : 0;
        int v = x;
        #pragma unroll
        for (int off = 1; off < 64; off <<= 1) {
            int t = __shfl_up(v, off);
            if ((tid & 63) >= off) v += t;
        }
        if ((tid & 63) == 63) wsum[tid >> 6] = v;
        __syncthreads();
        if (tid < 16) {
            int t = wsum[tid];
            #pragma unroll
            for (int off = 1; off < 16; off <<= 1) {
                int u = __shfl_up(t, off);
                if (tid >= off) t += u;
            }
            wsum[tid] = t;
        }
        __syncthreads();
        int woff = (tid >= 64) ? wsum[(tid >> 6) - 1] : 0;
        int incl = v + woff + carry;
        if (base + tid < nN) rowp[base + tid] = incl - x;
        __syncthreads();
        if (tid == 1023) carry = incl;
        __syncthreads();
    }
    if (tid == 0) rowp[nN] = carry;
}

__global__ __launch_bounds__(256) void scatter_kernel(
    const int* __restrict__ src, const int* __restrict__ dst,
    const int* __restrict__ rowp, int* __restrict__ cursor,
    int* __restrict__ perm, int* __restrict__ srcp, int* __restrict__ dstp, int nE)
{
    for (int e = blockIdx.x * 256 + threadIdx.x; e < nE; e += gridDim.x * 256) {
        int d = dst[e];
        int pos = rowp[d] + atomicAdd(&cursor[d], 1);
        perm[pos] = e;
        srcp[pos] = src[e];
        dstp[pos] = d;
    }
}

// ---------------- VM tower + scoring ----------------
__global__ void w2sum_kernel(const float* __restrict__ W2, const float* __restrict__ b2,
                             float* __restrict__ w2s)
{
    int j = threadIdx.x;  // 128 threads
    float s = 0.f;
    for (int o = 0; o < 64; o++) s += W2[j * 64 + o];
    w2s[j] = s;
    if (j == 0) {
        float bs = 0.f;
        for (int o = 0; o < 64; o++) bs += b2[o];
        w2s[128] = bs;
    }
}

__global__ __launch_bounds__(256) void vm_kernel(
    const float* __restrict__ vmf, const float* __restrict__ W1,
    const float* __restrict__ b1, const float* __restrict__ w2s,
    float* __restrict__ vm_sum, int nV)
{
    const int lane = threadIdx.x & 63;
    const int grp  = threadIdx.x >> 6;
    for (int v = blockIdx.x * 4 + grp; v < nV; v += gridDim.x * 4) {
        const float* vr = vmf + (long long)v * 64;
        float a0 = b1[lane], a1 = b1[lane + 64];
        #pragma unroll 4
        for (int k = 0; k < 64; k += 4) {
            float4 x = *reinterpret_cast<const float4*>(vr + k);
            a0 = fmaf(x.x, W1[(k + 0) * 128 + lane], a0);
            a0 = fmaf(x.y, W1[(k + 1) * 128 + lane], a0);
            a0 = fmaf(x.z, W1[(k + 2) * 128 + lane], a0);
            a0 = fmaf(x.w, W1[(k + 3) * 128 + lane], a0);
            a1 = fmaf(x.x, W1[(k + 0) * 128 + lane + 64], a1);
            a1 = fmaf(x.y, W1[(k + 1) * 128 + lane + 64], a1);
            a1 = fmaf(x.z, W1[(k + 2) * 128 + lane + 64], a1);
            a1 = fmaf(x.w, W1[(k + 3) * 128 + lane + 64], a1);
        }
        float part = fmaxf(a0, 0.f) * w2s[lane] + fmaxf(a1, 0.f) * w2s[lane + 64];
        #pragma unroll
        for (int off = 32; off > 0; off >>= 1) part += __shfl_down(part, off);
        if (lane == 0) vm_sum[v] = part + w2s[128];
    }
}

__global__ __launch_bounds__(256) void score_kernel(
    const int* __restrict__ ec, const int* __restrict__ ev,
    const float* __restrict__ ns, const float* __restrict__ vs,
    float* __restrict__ out, int n)
{
    int i = blockIdx.x * blockDim.x + threadIdx.x;
    if (i < n) {
        float x = ns[ec[i]] + vs[ev[i]];
        out[i] = 1.f / (1.f + expf(-x));
    }
}

extern "C" void kernel_launch(void* const* d_in, const int* in_sizes, int n_in,
                              void* d_out, int out_size, void* d_ws, size_t ws_size,
                              hipStream_t stream)
{
    const float* comp = (const float*)d_in[0];
    const float* ef   = (const float*)d_in[1];
    const float* vmf  = (const float*)d_in[2];
    const int*   src  = (const int*)d_in[3];
    const int*   dst  = (const int*)d_in[4];
    const int*   ecmp = (const int*)d_in[5];
    const int*   evm  = (const int*)d_in[6];
    const float* Wm1 = (const float*)d_in[7];  const float* bm1 = (const float*)d_in[8];
    const float* Wa1 = (const float*)d_in[9];  const float* ba1 = (const float*)d_in[10];
    const float* Wm2 = (const float*)d_in[11]; const float* bm2 = (const float*)d_in[12];
    const float* Wa2 = (const float*)d_in[13]; const float* ba2 = (const float*)d_in[14];
    const float* Wm3 = (const float*)d_in[15]; const float* bm3 = (const float*)d_in[16];
    const float* Wa3 = (const float*)d_in[17]; const float* ba3 = (const float*)d_in[18];
    const float* W1  = (const float*)d_in[19]; const float* b1  = (const float*)d_in[20];
    const float* W2  = (const float*)d_in[21]; const float* b2  = (const float*)d_in[22];

    const int nN = in_sizes[0] / 128;
    const int nE = in_sizes[3];
    const int nV = in_sizes[2] / 64;
    const int nS = in_sizes[5];

    // ---- workspace layout
    float* ws = (float*)d_ws;
    float* bufA     = ws;                        // nN*64: h1(52) / P3(64)
    float* bufB     = bufA + (size_t)nN * 64;    // nN*64: P1(64) / P2(32) / h2(28)
    float* ng       = bufB + (size_t)nN * 64;    // nN*64 neighbor accumulator
    float* node_sum = ng + (size_t)nN * 64;      // nN
    float* vm_sum   = node_sum + nN;             // nV
    float* w2s      = vm_sum + nV;               // 129
    int*   iws      = (int*)(w2s + 132);
    int*   deg      = iws;                       // nN
    int*   rowp     = deg + nN;                  // nN+1
    int*   cursor   = rowp + nN + 1;             // nN
    int*   perm     = cursor + nN;               // nE
    int*   srcp     = perm + nE;                 // nE
    int*   dstp     = srcp + nE;                 // nE

    float* h1 = bufA;   // stride 52
    float* h2 = bufB;   // stride 28
    float* P1 = bufB;   // stride 64
    float* P2 = bufB;   // stride 32
    float* P3 = bufA;   // stride 64

    const int ngrid = (nN + 127) / 128;
    const int egrid = (nE + 127) / 128;
    const int sgrid = (nE + 255) / 256 < 4096 ? (nE + 255) / 256 : 4096;
    const size_t ngbytes = (size_t)nN * 64 * sizeof(float);

    // ---- one-time counting sort of edges by dst
    hipMemsetAsync(deg, 0, (size_t)nN * sizeof(int), stream);
    hist_kernel<<<sgrid, 256, 0, stream>>>(dst, deg, nE);
    scan_kernel<<<1, 1024, 0, stream>>>(deg, rowp, nN);
    hipMemsetAsync(cursor, 0, (size_t)nN * sizeof(int), stream);
    scatter_kernel<<<sgrid, 256, 0, stream>>>(src, dst, rowp, cursor, perm, srcp, dstp, nE);

    // ================= Layer 1 (D=128 -> 50) =================
    hipMemsetAsync(ng, 0, ngbytes, stream);
    tile_gemm<128,128, 0,0, 64, 50, 16, 8, 0, false><<<ngrid, 256, 0, stream>>>(
        comp, 128, nullptr, 0, Wm1, bm1, nullptr, nullptr, nullptr, nullptr, 0, P1, 64, nN);
    tile_gemm<64,64, 0,0, 64, 50, 16, 8, 3, true><<<egrid, 256, 0, stream>>>(
        ef, 64, nullptr, 0, Wm1 + 128 * 50, nullptr, perm, srcp, dstp, P1, 64, ng, 64, nE);
    tile_gemm<128,128, 50,52, 60, 50, 16, 8, 1, false><<<ngrid, 256, 0, stream>>>(
        comp, 128, ng, 64, Wa1, ba1, nullptr, nullptr, nullptr, nullptr, 0, h1, 52, nN);

    // ================= Layer 2 (50 -> 25) =================
    hipMemsetAsync(ng, 0, ngbytes, stream);
    tile_gemm<50,52, 0,0, 52, 25, 8, 4, 0, false><<<ngrid, 256, 0, stream>>>(
        h1, 52, nullptr, 0, Wm2, bm2, nullptr, nullptr, nullptr, nullptr, 0, P2, 32, nN);
    tile_gemm<64,64, 0,0, 64, 25, 8, 4, 3, true><<<egrid, 256, 0, stream>>>(
        ef, 64, nullptr, 0, Wm2 + 50 * 25, nullptr, perm, srcp, dstp, P2, 32, ng, 64, nE);
    tile_gemm<50,52, 25,28, 80, 25, 8, 4, 1, false><<<ngrid, 256, 0, stream>>>(
        h1, 52, ng, 64, Wa2, ba2, nullptr, nullptr, nullptr, nullptr, 0, h2, 28, nN);

    // ================= Layer 3 (25 -> 64, fused rowsum) =================
    hipMemsetAsync(ng, 0, ngbytes, stream);
    tile_gemm<25,28, 0,0, 28, 64, 16, 8, 0, false><<<ngrid, 256, 0, stream>>>(
        h2, 28, nullptr, 0, Wm3, bm3, nullptr, nullptr, nullptr, nullptr, 0, P3, 64, nN);
    tile_gemm<64,64, 0,0, 64, 64, 16, 8, 3, true><<<egrid, 256, 0, stream>>>(
        ef, 64, nullptr, 0, Wm3 + 25 * 64, nullptr, perm, srcp, dstp, P3, 64, ng, 64, nE);
    tile_gemm<25,28, 64,68, 48, 64, 16, 8, 2, false><<<ngrid, 256, 0, stream>>>(
        h2, 28, ng, 64, Wa3, ba3, nullptr, nullptr, nullptr, nullptr, 0, node_sum, 1, nN);

    // ================= VM tower (folded) + scores =================
    w2sum_kernel<<<1, 128, 0, stream>>>(W2, b2, w2s);
    vm_kernel<<<(nV + 3) / 4, 256, 0, stream>>>(vmf, W1, b1, w2s, vm_sum, nV);
    score_kernel<<<(nS + 255) / 256, 256, 0, stream>>>(ecmp, evm, node_sum, vm_sum, (float*)d_out, nS);
}

// Round 5
// 1671.919 us; speedup vs baseline: 2.7468x; 1.0270x over previous
//
#include <hip/hip_runtime.h>

// ---------------------------------------------------------------------------
// GNN scorer, round 5 (= round 4 resubmitted after infra failure):
//   One-time: counting-sort edges by dst (hist/scan/scatter); scatter also
//   permutes ef into sorted order (efp) so edge GEMMs stream linearly.
//   Per layer:
//     P = h @ Wm[:d] + bm                        (node pre-GEMM)
//     ng[dst] += relu(P[srcp] + efp @ We)        (edge GEMM, linear rows,
//                                                 run-length-reduced atomics)
//     h' = relu([h ; ng] @ Wa + ba)              (apply; L3 fused to rowsum)
//   VM tower folded via w2sum; sigmoid scoring. All fp32.
// ---------------------------------------------------------------------------

// MODE: 0 = store linear (P)     1 = relu+store    2 = relu+rowsum
//       3 = edge: relu(acc + P[srcp]) run-reduced atomicAdd into Y[dstp]
// GX: gather X0 rows through gperm (fallback edge path when efp doesn't fit)
template<int K0, int KP0, int K1, int KP1, int KC, int OUT, int NTC, int RPT,
         int MODE, bool GX>
__global__ __launch_bounds__(256) void tile_gemm(
    const float* __restrict__ X0, int sx0,
    const float* __restrict__ X1, int sx1,
    const float* __restrict__ Wg, const float* __restrict__ Bg,
    const int* __restrict__ gperm,
    const int* __restrict__ gsrc, const int* __restrict__ gdst,
    const float* __restrict__ P, int sp,
    float* __restrict__ Y, int sy, int nR)
{
    constexpr int KPT  = KP0 + KP1;
    constexpr int C4   = KC / 4;
    constexpr int OUTP = 4 * NTC;
    constexpr int NTR  = 256 / NTC;
    constexpr int TR   = NTR * RPT;
    static_assert(TR == 128, "tile must be 128 rows");
    static_assert(KPT % KC == 0, "KC must divide KPT");
    static_assert((KC & 3) == 0 && (KP0 & 3) == 0, "f4 alignment");

    __shared__ float4 Xl[TR * C4];
    __shared__ float4 Wl[KC * NTC];
    __shared__ float  __align__(16) bl[OUTP];
    __shared__ int    sl_src[128], sl_dst[128];

    const int tid = threadIdx.x;
    const int r0  = blockIdx.x * TR;

    for (int idx = tid; idx < OUTP; idx += 256)
        bl[idx] = (Bg != nullptr && idx < OUT) ? Bg[idx] : 0.f;
    if (MODE == 3 && tid < TR) {
        int gr = r0 + tid;
        sl_src[tid] = (gr < nR) ? gsrc[gr] : 0;
        sl_dst[tid] = (gr < nR) ? gdst[gr] : -1;
    }

    const int tc  = tid & (NTC - 1);
    const int tr  = tid / NTC;
    const int key = (RPT * tr) >> 3;

    float4 acc[RPT];
    #pragma unroll
    for (int i = 0; i < RPT; i++) acc[i] = make_float4(0.f, 0.f, 0.f, 0.f);

    for (int kc0 = 0; kc0 < KPT; kc0 += KC) {
        if (kc0 != 0) __syncthreads();
        // ---- stage X chunk (swizzled: Xl[r][(c + (r>>3)) % C4])
        for (int idx = tid; idx < TR * C4; idx += 256) {
            int r = idx / C4, c = idx - r * C4;
            int col = kc0 + 4 * c;
            int gr = r0 + r;
            float4 v = make_float4(0.f, 0.f, 0.f, 0.f);
            if (gr < nR) {
                long long xr = GX ? (long long)gperm[gr] : (long long)gr;
                if (KP1 == 0 || col < KP0)
                    v = *reinterpret_cast<const float4*>(X0 + xr * sx0 + col);
                else
                    v = *reinterpret_cast<const float4*>(X1 + xr * sx1 + (col - KP0));
            }
            int cs = c + ((r >> 3) % C4); if (cs >= C4) cs -= C4;
            Xl[r * C4 + cs] = v;
        }
        // ---- stage W chunk (zero-pad K gaps and out cols)
        for (int idx = tid; idx < KC * OUTP; idx += 256) {
            int kl = idx / OUTP, o = idx - kl * OUTP;
            int k = kc0 + kl;
            float v = 0.f;
            if (o < OUT) {
                if (k < KP0) { if (k < K0) v = Wg[k * OUT + o]; }
                else { int kk = k - KP0; if (kk < K1) v = Wg[(K0 + kk) * OUT + o]; }
            }
            ((float*)Wl)[kl * OUTP + o] = v;
        }
        __syncthreads();

        const int km = key % C4;
        #pragma unroll 4
        for (int k4 = 0; k4 < C4; k4++) {
            int cs = k4 + km; if (cs >= C4) cs -= C4;
            float4 x[RPT];
            #pragma unroll
            for (int i = 0; i < RPT; i++)
                x[i] = Xl[(RPT * tr + i) * C4 + cs];
            #pragma unroll
            for (int kk = 0; kk < 4; kk++) {
                float4 w = Wl[(4 * k4 + kk) * NTC + tc];
                #pragma unroll
                for (int i = 0; i < RPT; i++) {
                    float xs = (kk == 0) ? x[i].x : (kk == 1) ? x[i].y
                             : (kk == 2) ? x[i].z : x[i].w;
                    acc[i].x = fmaf(xs, w.x, acc[i].x);
                    acc[i].y = fmaf(xs, w.y, acc[i].y);
                    acc[i].z = fmaf(xs, w.z, acc[i].z);
                    acc[i].w = fmaf(xs, w.w, acc[i].w);
                }
            }
        }
    }

    const float4 b4 = reinterpret_cast<float4*>(bl)[tc];
    const int o = 4 * tc;

    if (MODE == 0 || MODE == 1) {
        if (o < OUT) {
            #pragma unroll
            for (int i = 0; i < RPT; i++) {
                int gr = r0 + RPT * tr + i;
                if (gr < nR) {
                    float4 v;
                    v.x = acc[i].x + b4.x; v.y = acc[i].y + b4.y;
                    v.z = acc[i].z + b4.z; v.w = acc[i].w + b4.w;
                    if (MODE == 1) {
                        v.x = fmaxf(v.x, 0.f); v.y = fmaxf(v.y, 0.f);
                        v.z = fmaxf(v.z, 0.f); v.w = fmaxf(v.w, 0.f);
                    }
                    *reinterpret_cast<float4*>(Y + (long long)gr * sy + o) = v;
                }
            }
        }
    } else if (MODE == 2) {
        #pragma unroll
        for (int i = 0; i < RPT; i++) {
            int gr = r0 + RPT * tr + i;
            float s = fmaxf(acc[i].x + b4.x, 0.f) + fmaxf(acc[i].y + b4.y, 0.f)
                    + fmaxf(acc[i].z + b4.z, 0.f) + fmaxf(acc[i].w + b4.w, 0.f);
            #pragma unroll
            for (int off = 1; off < NTC; off <<= 1) s += __shfl_xor(s, off);
            if (tc == 0 && gr < nR) Y[gr] = s;
        }
    } else {  // MODE 3: edge epilogue with run-length-reduced atomics
        float4 run = make_float4(0.f, 0.f, 0.f, 0.f);
        int rund = -1;
        #pragma unroll
        for (int i = 0; i < RPT; i++) {
            int r = RPT * tr + i;
            int d = sl_dst[r];
            if (d >= 0) {
                int s = sl_src[r];
                float4 p = *reinterpret_cast<const float4*>(P + (long long)s * sp + o);
                float4 v;
                v.x = fmaxf(acc[i].x + p.x, 0.f);
                v.y = fmaxf(acc[i].y + p.y, 0.f);
                v.z = fmaxf(acc[i].z + p.z, 0.f);
                v.w = fmaxf(acc[i].w + p.w, 0.f);
                if (d != rund) {
                    if (rund >= 0) {
                        float* nb = Y + (long long)rund * sy + o;
                        if (o + 0 < OUT && run.x > 0.f) atomicAdd(nb + 0, run.x);
                        if (o + 1 < OUT && run.y > 0.f) atomicAdd(nb + 1, run.y);
                        if (o + 2 < OUT && run.z > 0.f) atomicAdd(nb + 2, run.z);
                        if (o + 3 < OUT && run.w > 0.f) atomicAdd(nb + 3, run.w);
                    }
                    run = v; rund = d;
                } else {
                    run.x += v.x; run.y += v.y; run.z += v.z; run.w += v.w;
                }
            }
        }
        if (rund >= 0) {
            float* nb = Y + (long long)rund * sy + o;
            if (o + 0 < OUT && run.x > 0.f) atomicAdd(nb + 0, run.x);
            if (o + 1 < OUT && run.y > 0.f) atomicAdd(nb + 1, run.y);
            if (o + 2 < OUT && run.z > 0.f) atomicAdd(nb + 2, run.z);
            if (o + 3 < OUT && run.w > 0.f) atomicAdd(nb + 3, run.w);
        }
    }
}

// ---------------- sort-by-dst (counting sort) ----------------
__global__ __launch_bounds__(256) void hist_kernel(
    const int* __restrict__ dst, int* __restrict__ deg, int nE)
{
    for (int e = blockIdx.x * 256 + threadIdx.x; e < nE; e += gridDim.x * 256)
        atomicAdd(&deg[dst[e]], 1);
}

__global__ __launch_bounds__(1024) void scan_kernel(
    const int* __restrict__ deg, int* __restrict__ rowp, int nN)
{
    __shared__ int wsum[16];
    __shared__ int carry;
    const int tid = threadIdx.x;
    if (tid == 0) carry = 0;
    __syncthreads();
    for (int base = 0; base < nN; base += 1024) {
        int x = (base + tid < nN) ? deg[base + tid] : 0;
        int v = x;
        #pragma unroll
        for (int off = 1; off < 64; off <<= 1) {
            int t = __shfl_up(v, off);
            if ((tid & 63) >= off) v += t;
        }
        if ((tid & 63) == 63) wsum[tid >> 6] = v;
        __syncthreads();
        if (tid < 16) {
            int t = wsum[tid];
            #pragma unroll
            for (int off = 1; off < 16; off <<= 1) {
                int u = __shfl_up(t, off);
                if (tid >= off) t += u;
            }
            wsum[tid] = t;
        }
        __syncthreads();
        int woff = (tid >= 64) ? wsum[(tid >> 6) - 1] : 0;
        int incl = v + woff + carry;
        if (base + tid < nN) rowp[base + tid] = incl - x;
        __syncthreads();
        if (tid == 1023) carry = incl;
        __syncthreads();
    }
    if (tid == 0) rowp[nN] = carry;
}

// COPY: also permute ef rows (64 floats) into sorted order -> efp
template<bool COPY>
__global__ __launch_bounds__(256) void scatter_kernel(
    const int* __restrict__ src, const int* __restrict__ dst,
    const int* __restrict__ rowp, int* __restrict__ cursor,
    const float* __restrict__ ef, float* __restrict__ efp,
    int* __restrict__ perm, int* __restrict__ srcp, int* __restrict__ dstp, int nE)
{
    for (int e = blockIdx.x * 256 + threadIdx.x; e < nE; e += gridDim.x * 256) {
        int d = dst[e];
        int pos = rowp[d] + atomicAdd(&cursor[d], 1);
        srcp[pos] = src[e];
        dstp[pos] = d;
        if (COPY) {
            const float4* er = reinterpret_cast<const float4*>(ef + (long long)e * 64);
            float4* eo = reinterpret_cast<float4*>(efp + (long long)pos * 64);
            #pragma unroll 4
            for (int i = 0; i < 16; i++) eo[i] = er[i];
        } else {
            perm[pos] = e;
        }
    }
}

// ---------------- VM tower + scoring ----------------
__global__ void w2sum_kernel(const float* __restrict__ W2, const float* __restrict__ b2,
                             float* __restrict__ w2s)
{
    int j = threadIdx.x;  // 128 threads
    float s = 0.f;
    for (int o = 0; o < 64; o++) s += W2[j * 64 + o];
    w2s[j] = s;
    if (j == 0) {
        float bs = 0.f;
        for (int o = 0; o < 64; o++) bs += b2[o];
        w2s[128] = bs;
    }
}

__global__ __launch_bounds__(256) void vm_kernel(
    const float* __restrict__ vmf, const float* __restrict__ W1,
    const float* __restrict__ b1, const float* __restrict__ w2s,
    float* __restrict__ vm_sum, int nV)
{
    const int lane = threadIdx.x & 63;
    const int grp  = threadIdx.x >> 6;
    for (int v = blockIdx.x * 4 + grp; v < nV; v += gridDim.x * 4) {
        const float* vr = vmf + (long long)v * 64;
        float a0 = b1[lane], a1 = b1[lane + 64];
        #pragma unroll 4
        for (int k = 0; k < 64; k += 4) {
            float4 x = *reinterpret_cast<const float4*>(vr + k);
            a0 = fmaf(x.x, W1[(k + 0) * 128 + lane], a0);
            a0 = fmaf(x.y, W1[(k + 1) * 128 + lane], a0);
            a0 = fmaf(x.z, W1[(k + 2) * 128 + lane], a0);
            a0 = fmaf(x.w, W1[(k + 3) * 128 + lane], a0);
            a1 = fmaf(x.x, W1[(k + 0) * 128 + lane + 64], a1);
            a1 = fmaf(x.y, W1[(k + 1) * 128 + lane + 64], a1);
            a1 = fmaf(x.z, W1[(k + 2) * 128 + lane + 64], a1);
            a1 = fmaf(x.w, W1[(k + 3) * 128 + lane + 64], a1);
        }
        float part = fmaxf(a0, 0.f) * w2s[lane] + fmaxf(a1, 0.f) * w2s[lane + 64];
        #pragma unroll
        for (int off = 32; off > 0; off >>= 1) part += __shfl_down(part, off);
        if (lane == 0) vm_sum[v] = part + w2s[128];
    }
}

__global__ __launch_bounds__(256) void score_kernel(
    const int* __restrict__ ec, const int* __restrict__ ev,
    const float* __restrict__ ns, const float* __restrict__ vs,
    float* __restrict__ out, int n)
{
    int i = blockIdx.x * blockDim.x + threadIdx.x;
    if (i < n) {
        float x = ns[ec[i]] + vs[ev[i]];
        out[i] = 1.f / (1.f + expf(-x));
    }
}

extern "C" void kernel_launch(void* const* d_in, const int* in_sizes, int n_in,
                              void* d_out, int out_size, void* d_ws, size_t ws_size,
                              hipStream_t stream)
{
    const float* comp = (const float*)d_in[0];
    const float* ef   = (const float*)d_in[1];
    const float* vmf  = (const float*)d_in[2];
    const int*   src  = (const int*)d_in[3];
    const int*   dst  = (const int*)d_in[4];
    const int*   ecmp = (const int*)d_in[5];
    const int*   evm  = (const int*)d_in[6];
    const float* Wm1 = (const float*)d_in[7];  const float* bm1 = (const float*)d_in[8];
    const float* Wa1 = (const float*)d_in[9];  const float* ba1 = (const float*)d_in[10];
    const float* Wm2 = (const float*)d_in[11]; const float* bm2 = (const float*)d_in[12];
    const float* Wa2 = (const float*)d_in[13]; const float* ba2 = (const float*)d_in[14];
    const float* Wm3 = (const float*)d_in[15]; const float* bm3 = (const float*)d_in[16];
    const float* Wa3 = (const float*)d_in[17]; const float* ba3 = (const float*)d_in[18];
    const float* W1  = (const float*)d_in[19]; const float* b1  = (const float*)d_in[20];
    const float* W2  = (const float*)d_in[21]; const float* b2  = (const float*)d_in[22];

    const int nN = in_sizes[0] / 128;
    const int nE = in_sizes[3];
    const int nV = in_sizes[2] / 64;
    const int nS = in_sizes[5];

    // ---- workspace layout
    float* ws = (float*)d_ws;
    float* bufA     = ws;                        // nN*64: h1(52) / P3(64)
    float* bufB     = bufA + (size_t)nN * 64;    // nN*64: P1(64) / P2(32) / h2(28)
    float* ng       = bufB + (size_t)nN * 64;    // nN*64 neighbor accumulator
    float* node_sum = ng + (size_t)nN * 64;      // nN
    float* vm_sum   = node_sum + nN;             // nV
    float* w2s      = vm_sum + nV;               // 132
    int*   iws      = (int*)(w2s + 132);
    int*   deg      = iws;                       // nN
    int*   rowp     = deg + nN;                  // nN+1
    int*   cursor   = rowp + nN + 1;             // nN
    int*   srcp     = cursor + nN;               // nE
    int*   dstp     = srcp + nE;                 // nE
    int*   perm     = dstp + nE;                 // nE (fallback only)
    // efp after perm, aligned to 16B
    size_t used_i   = (size_t)(perm + nE - (int*)d_ws);   // ints used
    size_t efp_off  = (used_i * 4 + 15) & ~(size_t)15;
    float* efp      = (float*)((char*)d_ws + efp_off);
    const bool use_efp = (efp_off + (size_t)nE * 64 * sizeof(float)) <= ws_size;

    float* h1 = bufA;   // stride 52
    float* h2 = bufB;   // stride 28
    float* P1 = bufB;   // stride 64
    float* P2 = bufB;   // stride 32
    float* P3 = bufA;   // stride 64

    const int ngrid = (nN + 127) / 128;
    const int egrid = (nE + 127) / 128;
    const int sgrid = (nE + 255) / 256 < 4096 ? (nE + 255) / 256 : 4096;
    const size_t ngbytes = (size_t)nN * 64 * sizeof(float);

    // ---- one-time counting sort of edges by dst (+ ef permute)
    hipMemsetAsync(deg, 0, (size_t)nN * sizeof(int), stream);
    hist_kernel<<<sgrid, 256, 0, stream>>>(dst, deg, nE);
    scan_kernel<<<1, 1024, 0, stream>>>(deg, rowp, nN);
    hipMemsetAsync(cursor, 0, (size_t)nN * sizeof(int), stream);
    if (use_efp)
        scatter_kernel<true><<<sgrid, 256, 0, stream>>>(src, dst, rowp, cursor, ef, efp, perm, srcp, dstp, nE);
    else
        scatter_kernel<false><<<sgrid, 256, 0, stream>>>(src, dst, rowp, cursor, ef, efp, perm, srcp, dstp, nE);

    // ================= Layer 1 (D=128 -> 50) =================
    hipMemsetAsync(ng, 0, ngbytes, stream);
    tile_gemm<128,128, 0,0, 64, 50, 16, 8, 0, false><<<ngrid, 256, 0, stream>>>(
        comp, 128, nullptr, 0, Wm1, bm1, nullptr, nullptr, nullptr, nullptr, 0, P1, 64, nN);
    if (use_efp)
        tile_gemm<64,64, 0,0, 32, 50, 16, 8, 3, false><<<egrid, 256, 0, stream>>>(
            efp, 64, nullptr, 0, Wm1 + 128 * 50, nullptr, nullptr, srcp, dstp, P1, 64, ng, 64, nE);
    else
        tile_gemm<64,64, 0,0, 32, 50, 16, 8, 3, true><<<egrid, 256, 0, stream>>>(
            ef, 64, nullptr, 0, Wm1 + 128 * 50, nullptr, perm, srcp, dstp, P1, 64, ng, 64, nE);
    tile_gemm<128,128, 50,52, 60, 50, 16, 8, 1, false><<<ngrid, 256, 0, stream>>>(
        comp, 128, ng, 64, Wa1, ba1, nullptr, nullptr, nullptr, nullptr, 0, h1, 52, nN);

    // ================= Layer 2 (50 -> 25) =================
    hipMemsetAsync(ng, 0, ngbytes, stream);
    tile_gemm<50,52, 0,0, 52, 25, 8, 4, 0, false><<<ngrid, 256, 0, stream>>>(
        h1, 52, nullptr, 0, Wm2, bm2, nullptr, nullptr, nullptr, nullptr, 0, P2, 32, nN);
    if (use_efp)
        tile_gemm<64,64, 0,0, 32, 25, 8, 4, 3, false><<<egrid, 256, 0, stream>>>(
            efp, 64, nullptr, 0, Wm2 + 50 * 25, nullptr, nullptr, srcp, dstp, P2, 32, ng, 64, nE);
    else
        tile_gemm<64,64, 0,0, 32, 25, 8, 4, 3, true><<<egrid, 256, 0, stream>>>(
            ef, 64, nullptr, 0, Wm2 + 50 * 25, nullptr, perm, srcp, dstp, P2, 32, ng, 64, nE);
    tile_gemm<50,52, 25,28, 80, 25, 8, 4, 1, false><<<ngrid, 256, 0, stream>>>(
        h1, 52, ng, 64, Wa2, ba2, nullptr, nullptr, nullptr, nullptr, 0, h2, 28, nN);

    // ================= Layer 3 (25 -> 64, fused rowsum) =================
    hipMemsetAsync(ng, 0, ngbytes, stream);
    tile_gemm<25,28, 0,0, 28, 64, 16, 8, 0, false><<<ngrid, 256, 0, stream>>>(
        h2, 28, nullptr, 0, Wm3, bm3, nullptr, nullptr, nullptr, nullptr, 0, P3, 64, nN);
    if (use_efp)
        tile_gemm<64,64, 0,0, 32, 64, 16, 8, 3, false><<<egrid, 256, 0, stream>>>(
            efp, 64, nullptr, 0, Wm3 + 25 * 64, nullptr, nullptr, srcp, dstp, P3, 64, ng, 64, nE);
    else
        tile_gemm<64,64, 0,0, 32, 64, 16, 8, 3, true><<<egrid, 256, 0, stream>>>(
            ef, 64, nullptr, 0, Wm3 + 25 * 64, nullptr, perm, srcp, dstp, P3, 64, ng, 64, nE);
    tile_gemm<25,28, 64,68, 48, 64, 16, 8, 2, false><<<ngrid, 256, 0, stream>>>(
        h2, 28, ng, 64, Wa3, ba3, nullptr, nullptr, nullptr, nullptr, 0, node_sum, 1, nN);

    // ================= VM tower (folded) + scores =================
    w2sum_kernel<<<1, 128, 0, stream>>>(W2, b2, w2s);
    vm_kernel<<<(nV + 3) / 4, 256, 0, stream>>>(vmf, W1, b1, w2s, vm_sum, nV);
    score_kernel<<<(nS + 255) / 256, 256, 0, stream>>>(ecmp, evm, node_sum, vm_sum, (float*)d_out, nS);
}

// Round 6
// 1501.861 us; speedup vs baseline: 3.0578x; 1.1132x over previous
//
#include <hip/hip_runtime.h>

// ---------------------------------------------------------------------------
// GNN scorer, round 6:
//   One-time: counting-sort indices by dst (hist/scan/scatter-light).
//   Layer 1 edge GEMM gathers ef[perm] (random read) and FUSES the permute:
//   writes staged rows linearly to efp; L2/L3 edge GEMMs stream efp linearly.
//   Per layer:
//     P = h @ Wm[:d] + bm                        (node pre-GEMM)
//     ng[dst] += relu(P[srcp] + ef_l @ We)       (edge GEMM, run-reduced atomics)
//     h' = relu([h ; ng] @ Wa + ba)              (apply; L3 fused to rowsum)
//   VM tower folded via w2sum; sigmoid scoring. All fp32.
// ---------------------------------------------------------------------------

// MODE: 0 = store linear (P)     1 = relu+store    2 = relu+rowsum
//       3 = edge: relu(acc + P[srcp]) run-reduced atomicAdd into Y[dstp]
// GX:   gather X0 rows through gperm
// WEFP: write staged X rows linearly to efp_out (fused permute, L1 edge only)
template<int K0, int KP0, int K1, int KP1, int KC, int OUT, int NTC, int RPT,
         int MODE, bool GX, bool WEFP>
__global__ __launch_bounds__(256) void tile_gemm(
    const float* __restrict__ X0, int sx0,
    const float* __restrict__ X1, int sx1,
    const float* __restrict__ Wg, const float* __restrict__ Bg,
    const int* __restrict__ gperm,
    const int* __restrict__ gsrc, const int* __restrict__ gdst,
    const float* __restrict__ P, int sp,
    float* __restrict__ efp_out,
    float* __restrict__ Y, int sy, int nR)
{
    constexpr int KPT  = KP0 + KP1;
    constexpr int C4   = KC / 4;
    constexpr int OUTP = 4 * NTC;
    constexpr int NTR  = 256 / NTC;
    constexpr int TR   = NTR * RPT;
    static_assert(TR == 128, "tile must be 128 rows");
    static_assert(KPT % KC == 0, "KC must divide KPT");
    static_assert((KC & 3) == 0 && (KP0 & 3) == 0, "f4 alignment");

    __shared__ float4 Xl[TR * C4];
    __shared__ float4 Wl[KC * NTC];
    __shared__ float  __align__(16) bl[OUTP];
    __shared__ int    sl_src[128], sl_dst[128];

    const int tid = threadIdx.x;
    const int r0  = blockIdx.x * TR;

    for (int idx = tid; idx < OUTP; idx += 256)
        bl[idx] = (Bg != nullptr && idx < OUT) ? Bg[idx] : 0.f;
    if (MODE == 3 && tid < TR) {
        int gr = r0 + tid;
        sl_src[tid] = (gr < nR) ? gsrc[gr] : 0;
        sl_dst[tid] = (gr < nR) ? gdst[gr] : -1;
    }

    const int tc  = tid & (NTC - 1);
    const int tr  = tid / NTC;
    const int key = (RPT * tr) >> 3;

    float4 acc[RPT];
    #pragma unroll
    for (int i = 0; i < RPT; i++) acc[i] = make_float4(0.f, 0.f, 0.f, 0.f);

    for (int kc0 = 0; kc0 < KPT; kc0 += KC) {
        if (kc0 != 0) __syncthreads();
        // ---- stage X chunk (swizzled: Xl[r][(c + (r>>3)) % C4])
        for (int idx = tid; idx < TR * C4; idx += 256) {
            int r = idx / C4, c = idx - r * C4;
            int col = kc0 + 4 * c;
            int gr = r0 + r;
            float4 v = make_float4(0.f, 0.f, 0.f, 0.f);
            if (gr < nR) {
                long long xr = GX ? (long long)gperm[gr] : (long long)gr;
                if (KP1 == 0 || col < KP0)
                    v = *reinterpret_cast<const float4*>(X0 + xr * sx0 + col);
                else
                    v = *reinterpret_cast<const float4*>(X1 + xr * sx1 + (col - KP0));
                if (WEFP)
                    *reinterpret_cast<float4*>(efp_out + (long long)gr * 64 + col) = v;
            }
            int cs = c + ((r >> 3) % C4); if (cs >= C4) cs -= C4;
            Xl[r * C4 + cs] = v;
        }
        // ---- stage W chunk (zero-pad K gaps and out cols)
        for (int idx = tid; idx < KC * OUTP; idx += 256) {
            int kl = idx / OUTP, o = idx - kl * OUTP;
            int k = kc0 + kl;
            float v = 0.f;
            if (o < OUT) {
                if (k < KP0) { if (k < K0) v = Wg[k * OUT + o]; }
                else { int kk = k - KP0; if (kk < K1) v = Wg[(K0 + kk) * OUT + o]; }
            }
            ((float*)Wl)[kl * OUTP + o] = v;
        }
        __syncthreads();

        const int km = key % C4;
        #pragma unroll 4
        for (int k4 = 0; k4 < C4; k4++) {
            int cs = k4 + km; if (cs >= C4) cs -= C4;
            float4 x[RPT];
            #pragma unroll
            for (int i = 0; i < RPT; i++)
                x[i] = Xl[(RPT * tr + i) * C4 + cs];
            #pragma unroll
            for (int kk = 0; kk < 4; kk++) {
                float4 w = Wl[(4 * k4 + kk) * NTC + tc];
                #pragma unroll
                for (int i = 0; i < RPT; i++) {
                    float xs = (kk == 0) ? x[i].x : (kk == 1) ? x[i].y
                             : (kk == 2) ? x[i].z : x[i].w;
                    acc[i].x = fmaf(xs, w.x, acc[i].x);
                    acc[i].y = fmaf(xs, w.y, acc[i].y);
                    acc[i].z = fmaf(xs, w.z, acc[i].z);
                    acc[i].w = fmaf(xs, w.w, acc[i].w);
                }
            }
        }
    }

    const float4 b4 = reinterpret_cast<float4*>(bl)[tc];
    const int o = 4 * tc;

    if (MODE == 0 || MODE == 1) {
        if (o < OUT) {
            #pragma unroll
            for (int i = 0; i < RPT; i++) {
                int gr = r0 + RPT * tr + i;
                if (gr < nR) {
                    float4 v;
                    v.x = acc[i].x + b4.x; v.y = acc[i].y + b4.y;
                    v.z = acc[i].z + b4.z; v.w = acc[i].w + b4.w;
                    if (MODE == 1) {
                        v.x = fmaxf(v.x, 0.f); v.y = fmaxf(v.y, 0.f);
                        v.z = fmaxf(v.z, 0.f); v.w = fmaxf(v.w, 0.f);
                    }
                    *reinterpret_cast<float4*>(Y + (long long)gr * sy + o) = v;
                }
            }
        }
    } else if (MODE == 2) {
        #pragma unroll
        for (int i = 0; i < RPT; i++) {
            int gr = r0 + RPT * tr + i;
            float s = fmaxf(acc[i].x + b4.x, 0.f) + fmaxf(acc[i].y + b4.y, 0.f)
                    + fmaxf(acc[i].z + b4.z, 0.f) + fmaxf(acc[i].w + b4.w, 0.f);
            #pragma unroll
            for (int off = 1; off < NTC; off <<= 1) s += __shfl_xor(s, off);
            if (tc == 0 && gr < nR) Y[gr] = s;
        }
    } else {  // MODE 3: edge epilogue with run-length-reduced atomics
        float4 run = make_float4(0.f, 0.f, 0.f, 0.f);
        int rund = -1;
        #pragma unroll
        for (int i = 0; i < RPT; i++) {
            int r = RPT * tr + i;
            int d = sl_dst[r];
            if (d >= 0) {
                int s = sl_src[r];
                float4 p = *reinterpret_cast<const float4*>(P + (long long)s * sp + o);
                float4 v;
                v.x = fmaxf(acc[i].x + p.x, 0.f);
                v.y = fmaxf(acc[i].y + p.y, 0.f);
                v.z = fmaxf(acc[i].z + p.z, 0.f);
                v.w = fmaxf(acc[i].w + p.w, 0.f);
                if (d != rund) {
                    if (rund >= 0) {
                        float* nb = Y + (long long)rund * sy + o;
                        if (o + 0 < OUT && run.x > 0.f) atomicAdd(nb + 0, run.x);
                        if (o + 1 < OUT && run.y > 0.f) atomicAdd(nb + 1, run.y);
                        if (o + 2 < OUT && run.z > 0.f) atomicAdd(nb + 2, run.z);
                        if (o + 3 < OUT && run.w > 0.f) atomicAdd(nb + 3, run.w);
                    }
                    run = v; rund = d;
                } else {
                    run.x += v.x; run.y += v.y; run.z += v.z; run.w += v.w;
                }
            }
        }
        if (rund >= 0) {
            float* nb = Y + (long long)rund * sy + o;
            if (o + 0 < OUT && run.x > 0.f) atomicAdd(nb + 0, run.x);
            if (o + 1 < OUT && run.y > 0.f) atomicAdd(nb + 1, run.y);
            if (o + 2 < OUT && run.z > 0.f) atomicAdd(nb + 2, run.z);
            if (o + 3 < OUT && run.w > 0.f) atomicAdd(nb + 3, run.w);
        }
    }
}

// ---------------- sort-by-dst (counting sort, index-only) ----------------
__global__ __launch_bounds__(256) void hist_kernel(
    const int* __restrict__ dst, int* __restrict__ deg, int nE)
{
    for (int e = blockIdx.x * 256 + threadIdx.x; e < nE; e += gridDim.x * 256)
        atomicAdd(&deg[dst[e]], 1);
}

__global__ __launch_bounds__(1024) void scan_kernel(
    const int* __restrict__ deg, int* __restrict__ rowp, int nN)
{
    __shared__ int wsum[16];
    __shared__ int carry;
    const int tid = threadIdx.x;
    if (tid == 0) carry = 0;
    __syncthreads();
    for (int base = 0; base < nN; base += 1024) {
        int x = (base + tid < nN) ? deg[base + tid] : 0;
        int v = x;
        #pragma unroll
        for (int off = 1; off < 64; off <<= 1) {
            int t = __shfl_up(v, off);
            if ((tid & 63) >= off) v += t;
        }
        if ((tid & 63) == 63) wsum[tid >> 6] = v;
        __syncthreads();
        if (tid < 16) {
            int t = wsum[tid];
            #pragma unroll
            for (int off = 1; off < 16; off <<= 1) {
                int u = __shfl_up(t, off);
                if (tid >= off) t += u;
            }
            wsum[tid] = t;
        }
        __syncthreads();
        int woff = (tid >= 64) ? wsum[(tid >> 6) - 1] : 0;
        int incl = v + woff + carry;
        if (base + tid < nN) rowp[base + tid] = incl - x;
        __syncthreads();
        if (tid == 1023) carry = incl;
        __syncthreads();
    }
    if (tid == 0) rowp[nN] = carry;
}

__global__ __launch_bounds__(256) void scatter_kernel(
    const int* __restrict__ src, const int* __restrict__ dst,
    const int* __restrict__ rowp, int* __restrict__ cursor,
    int* __restrict__ perm, int* __restrict__ srcp, int* __restrict__ dstp, int nE)
{
    for (int e = blockIdx.x * 256 + threadIdx.x; e < nE; e += gridDim.x * 256) {
        int d = dst[e];
        int pos = rowp[d] + atomicAdd(&cursor[d], 1);
        perm[pos] = e;
        srcp[pos] = src[e];
        dstp[pos] = d;
    }
}

// ---------------- VM tower + scoring ----------------
__global__ void w2sum_kernel(const float* __restrict__ W2, const float* __restrict__ b2,
                             float* __restrict__ w2s)
{
    int j = threadIdx.x;  // 128 threads
    float s = 0.f;
    for (int o = 0; o < 64; o++) s += W2[j * 64 + o];
    w2s[j] = s;
    if (j == 0) {
        float bs = 0.f;
        for (int o = 0; o < 64; o++) bs += b2[o];
        w2s[128] = bs;
    }
}

__global__ __launch_bounds__(256) void vm_kernel(
    const float* __restrict__ vmf, const float* __restrict__ W1,
    const float* __restrict__ b1, const float* __restrict__ w2s,
    float* __restrict__ vm_sum, int nV)
{
    const int lane = threadIdx.x & 63;
    const int grp  = threadIdx.x >> 6;
    for (int v = blockIdx.x * 4 + grp; v < nV; v += gridDim.x * 4) {
        const float* vr = vmf + (long long)v * 64;
        float a0 = b1[lane], a1 = b1[lane + 64];
        #pragma unroll 4
        for (int k = 0; k < 64; k += 4) {
            float4 x = *reinterpret_cast<const float4*>(vr + k);
            a0 = fmaf(x.x, W1[(k + 0) * 128 + lane], a0);
            a0 = fmaf(x.y, W1[(k + 1) * 128 + lane], a0);
            a0 = fmaf(x.z, W1[(k + 2) * 128 + lane], a0);
            a0 = fmaf(x.w, W1[(k + 3) * 128 + lane], a0);
            a1 = fmaf(x.x, W1[(k + 0) * 128 + lane + 64], a1);
            a1 = fmaf(x.y, W1[(k + 1) * 128 + lane + 64], a1);
            a1 = fmaf(x.z, W1[(k + 2) * 128 + lane + 64], a1);
            a1 = fmaf(x.w, W1[(k + 3) * 128 + lane + 64], a1);
        }
        float part = fmaxf(a0, 0.f) * w2s[lane] + fmaxf(a1, 0.f) * w2s[lane + 64];
        #pragma unroll
        for (int off = 32; off > 0; off >>= 1) part += __shfl_down(part, off);
        if (lane == 0) vm_sum[v] = part + w2s[128];
    }
}

__global__ __launch_bounds__(256) void score_kernel(
    const int* __restrict__ ec, const int* __restrict__ ev,
    const float* __restrict__ ns, const float* __restrict__ vs,
    float* __restrict__ out, int n)
{
    int i = blockIdx.x * blockDim.x + threadIdx.x;
    if (i < n) {
        float x = ns[ec[i]] + vs[ev[i]];
        out[i] = 1.f / (1.f + expf(-x));
    }
}

extern "C" void kernel_launch(void* const* d_in, const int* in_sizes, int n_in,
                              void* d_out, int out_size, void* d_ws, size_t ws_size,
                              hipStream_t stream)
{
    const float* comp = (const float*)d_in[0];
    const float* ef   = (const float*)d_in[1];
    const float* vmf  = (const float*)d_in[2];
    const int*   src  = (const int*)d_in[3];
    const int*   dst  = (const int*)d_in[4];
    const int*   ecmp = (const int*)d_in[5];
    const int*   evm  = (const int*)d_in[6];
    const float* Wm1 = (const float*)d_in[7];  const float* bm1 = (const float*)d_in[8];
    const float* Wa1 = (const float*)d_in[9];  const float* ba1 = (const float*)d_in[10];
    const float* Wm2 = (const float*)d_in[11]; const float* bm2 = (const float*)d_in[12];
    const float* Wa2 = (const float*)d_in[13]; const float* ba2 = (const float*)d_in[14];
    const float* Wm3 = (const float*)d_in[15]; const float* bm3 = (const float*)d_in[16];
    const float* Wa3 = (const float*)d_in[17]; const float* ba3 = (const float*)d_in[18];
    const float* W1  = (const float*)d_in[19]; const float* b1  = (const float*)d_in[20];
    const float* W2  = (const float*)d_in[21]; const float* b2  = (const float*)d_in[22];

    const int nN = in_sizes[0] / 128;
    const int nE = in_sizes[3];
    const int nV = in_sizes[2] / 64;
    const int nS = in_sizes[5];

    // ---- workspace layout
    float* ws = (float*)d_ws;
    float* bufA     = ws;                        // nN*64: h1(52) / P3(64)
    float* bufB     = bufA + (size_t)nN * 64;    // nN*64: P1(64) / P2(32) / h2(28)
    float* ng       = bufB + (size_t)nN * 64;    // nN*64 neighbor accumulator
    float* node_sum = ng + (size_t)nN * 64;      // nN
    float* vm_sum   = node_sum + nN;             // nV
    float* w2s      = vm_sum + nV;               // 132
    int*   iws      = (int*)(w2s + 132);
    int*   deg      = iws;                       // nN
    int*   rowp     = deg + nN;                  // nN+1
    int*   cursor   = rowp + nN + 1;             // nN
    int*   srcp     = cursor + nN;               // nE
    int*   dstp     = srcp + nE;                 // nE
    int*   perm     = dstp + nE;                 // nE
    // efp after perm, aligned to 256B (whole-cache-line rows)
    size_t used_i   = (size_t)(perm + nE - (int*)d_ws);   // ints used
    size_t efp_off  = (used_i * 4 + 255) & ~(size_t)255;
    float* efp      = (float*)((char*)d_ws + efp_off);
    const bool use_efp = (efp_off + (size_t)nE * 64 * sizeof(float)) <= ws_size;

    float* h1 = bufA;   // stride 52
    float* h2 = bufB;   // stride 28
    float* P1 = bufB;   // stride 64
    float* P2 = bufB;   // stride 32
    float* P3 = bufA;   // stride 64

    const int ngrid = (nN + 127) / 128;
    const int egrid = (nE + 127) / 128;
    const int sgrid = (nE + 255) / 256 < 4096 ? (nE + 255) / 256 : 4096;
    const size_t ngbytes = (size_t)nN * 64 * sizeof(float);

    // ---- one-time counting sort of edge indices by dst
    hipMemsetAsync(deg, 0, (size_t)nN * sizeof(int), stream);
    hist_kernel<<<sgrid, 256, 0, stream>>>(dst, deg, nE);
    scan_kernel<<<1, 1024, 0, stream>>>(deg, rowp, nN);
    hipMemsetAsync(cursor, 0, (size_t)nN * sizeof(int), stream);
    scatter_kernel<<<sgrid, 256, 0, stream>>>(src, dst, rowp, cursor, perm, srcp, dstp, nE);

    // ================= Layer 1 (D=128 -> 50) =================
    hipMemsetAsync(ng, 0, ngbytes, stream);
    tile_gemm<128,128, 0,0, 64, 50, 16, 8, 0, false, false><<<ngrid, 256, 0, stream>>>(
        comp, 128, nullptr, 0, Wm1, bm1, nullptr, nullptr, nullptr, nullptr, 0, nullptr, P1, 64, nN);
    if (use_efp)   // gather ef[perm] + fused linear write of efp
        tile_gemm<64,64, 0,0, 32, 50, 16, 8, 3, true, true><<<egrid, 256, 0, stream>>>(
            ef, 64, nullptr, 0, Wm1 + 128 * 50, nullptr, perm, srcp, dstp, P1, 64, efp, ng, 64, nE);
    else
        tile_gemm<64,64, 0,0, 32, 50, 16, 8, 3, true, false><<<egrid, 256, 0, stream>>>(
            ef, 64, nullptr, 0, Wm1 + 128 * 50, nullptr, perm, srcp, dstp, P1, 64, nullptr, ng, 64, nE);
    tile_gemm<128,128, 50,52, 60, 50, 16, 8, 1, false, false><<<ngrid, 256, 0, stream>>>(
        comp, 128, ng, 64, Wa1, ba1, nullptr, nullptr, nullptr, nullptr, 0, nullptr, h1, 52, nN);

    // ================= Layer 2 (50 -> 25) =================
    hipMemsetAsync(ng, 0, ngbytes, stream);
    tile_gemm<50,52, 0,0, 52, 25, 8, 4, 0, false, false><<<ngrid, 256, 0, stream>>>(
        h1, 52, nullptr, 0, Wm2, bm2, nullptr, nullptr, nullptr, nullptr, 0, nullptr, P2, 32, nN);
    if (use_efp)
        tile_gemm<64,64, 0,0, 32, 25, 8, 4, 3, false, false><<<egrid, 256, 0, stream>>>(
            efp, 64, nullptr, 0, Wm2 + 50 * 25, nullptr, nullptr, srcp, dstp, P2, 32, nullptr, ng, 64, nE);
    else
        tile_gemm<64,64, 0,0, 32, 25, 8, 4, 3, true, false><<<egrid, 256, 0, stream>>>(
            ef, 64, nullptr, 0, Wm2 + 50 * 25, nullptr, perm, srcp, dstp, P2, 32, nullptr, ng, 64, nE);
    tile_gemm<50,52, 25,28, 80, 25, 8, 4, 1, false, false><<<ngrid, 256, 0, stream>>>(
        h1, 52, ng, 64, Wa2, ba2, nullptr, nullptr, nullptr, nullptr, 0, nullptr, h2, 28, nN);

    // ================= Layer 3 (25 -> 64, fused rowsum) =================
    hipMemsetAsync(ng, 0, ngbytes, stream);
    tile_gemm<25,28, 0,0, 28, 64, 16, 8, 0, false, false><<<ngrid, 256, 0, stream>>>(
        h2, 28, nullptr, 0, Wm3, bm3, nullptr, nullptr, nullptr, nullptr, 0, nullptr, P3, 64, nN);
    if (use_efp)
        tile_gemm<64,64, 0,0, 32, 64, 16, 8, 3, false, false><<<egrid, 256, 0, stream>>>(
            efp, 64, nullptr, 0, Wm3 + 25 * 64, nullptr, nullptr, srcp, dstp, P3, 64, nullptr, ng, 64, nE);
    else
        tile_gemm<64,64, 0,0, 32, 64, 16, 8, 3, true, false><<<egrid, 256, 0, stream>>>(
            ef, 64, nullptr, 0, Wm3 + 25 * 64, nullptr, perm, srcp, dstp, P3, 64, nullptr, ng, 64, nE);
    tile_gemm<25,28, 64,68, 48, 64, 16, 8, 2, false, false><<<ngrid, 256, 0, stream>>>(
        h2, 28, ng, 64, Wa3, ba3, nullptr, nullptr, nullptr, nullptr, 0, nullptr, node_sum, 1, nN);

    // ================= VM tower (folded) + scores =================
    w2sum_kernel<<<1, 128, 0, stream>>>(W2, b2, w2s);
    vm_kernel<<<(nV + 3) / 4, 256, 0, stream>>>(vmf, W1, b1, w2s, vm_sum, nV);
    score_kernel<<<(nS + 255) / 256, 256, 0, stream>>>(ecmp, evm, node_sum, vm_sum, (float*)d_out, nS);
}